// Round 3
// baseline (151.353 us; speedup 1.0000x reference)
//
#include <hip/hip_runtime.h>

#define T_DIM 512
#define B_DIM 128
#define E_DIM 256
#define NEG_INF (-1e30f)
#define W_WIN 32      // t-window per workgroup
#define L_SLOTS 16    // staged shared-suffix rows

typedef float vfloat4 __attribute__((ext_vector_type(4)));  // native vec for nt-store

// Closed-form stack math (exact max-plus identity):
//   rc_t[tau] = S[t] + max_{m in [tau,t]} g[m],  S = incl. prefix sum of (d-u),
//   g[m] = d[m] - S[m].
//   W[t][tau] != 0 only at right-to-left records of g (NGL chain from t),
//   truncated once S[t] + g[m] >= 1.
// Sharing lemma: for any chain node x >= t0 with ngl(x) < t0, ngl(x) is a
// left-record of t0-1 (g[ngl(x)] > g over (ngl(x), x) superset of (ngl(x), t0-1]),
// and the chain then follows the record chain L of t0-1 consecutively.

struct Node { float g; int ngl; };   // g value + next-greater-to-left index

// Kernel 1: per-b prep. Shuffle wave-scan for S; sparse-table (range-max
// binary descend) for NGL: fixed 10 LDS probes per thread, no divergent scans.
__global__ void __launch_bounds__(512) scan_prep(
    const float* __restrict__ u, const float* __restrict__ d,
    float* __restrict__ S_out, Node* __restrict__ nodes)
{
    const int b    = blockIdx.x;
    const int t    = threadIdx.x;
    const int lane = t & 63;
    const int w    = t >> 6;          // 8 waves

    __shared__ float wsum[8];
    __shared__ float wpre[8];
    __shared__ float M[10][T_DIM];    // M[k][i] = max g over [max(0,i-2^k+1), i]

    const float dv = d[t * B_DIM + b];
    float x = dv - u[t * B_DIM + b];

    // wave-level inclusive scan (6 shfl steps)
    #pragma unroll
    for (int off = 1; off < 64; off <<= 1) {
        float y = __shfl_up(x, off, 64);
        if (lane >= off) x += y;
    }
    if (lane == 63) wsum[w] = x;
    __syncthreads();
    if (t < 8) {                       // tiny exclusive scan of 8 wave totals
        float s = 0.f;
        for (int i = 0; i < t; ++i) s += wsum[i];
        wpre[t] = s;
    }
    __syncthreads();
    const float S = x + wpre[w];       // inclusive prefix sum of (d-u)
    const float g = dv - S;

    // build sparse table: 9 levels of doubling window max
    M[0][t] = g;
    __syncthreads();
    #pragma unroll
    for (int k = 1; k < 10; ++k) {
        int h = 1 << (k - 1);
        float left = (t >= h) ? M[k - 1][t - h] : NEG_INF;
        float mk = fmaxf(M[k - 1][t], left);
        __syncthreads();               // level k-1 reads done
        M[k][t] = mk;
        __syncthreads();
    }

    // binary descend: largest m < t with g[m] > g (strict); else -1.
    int m = t - 1;
    #pragma unroll
    for (int k = 9; k >= 0; --k) {
        if (m >= 0 && M[k][m] <= g) m -= (1 << k);
    }
    if (m < 0) m = -1;

    S_out[(b << 9) | t] = S;
    nodes[(b << 9) | t] = Node{g, m};
}

// Kernel 2: windowed chain-sharing. One workgroup = (b, 32 consecutive t).
// Stage the 32 window v-rows + the shared below-window record chain L (rows
// gathered once) in LDS; walk all 32 chains from LDS. Cuts L3 v-row traffic
// from pairs*1KB (~400MB) to ~1x v (~75MB). Global-walk fallback for L
// overflow keeps correctness independent of the staging bound.
__global__ void __launch_bounds__(256) stack_read(
    const float* __restrict__ v, const float* __restrict__ S_in,
    const Node* __restrict__ nodes, float* __restrict__ out)
{
    __shared__ float vwin[W_WIN][E_DIM];   // 32 KB
    __shared__ float vL[L_SLOTS][E_DIM];   // 16 KB
    __shared__ float wg_g[W_WIN];
    __shared__ int   wg_ngl[W_WIN];
    __shared__ float wg_S[W_WIN];
    __shared__ int   Lidx[L_SLOTS];
    __shared__ float Lg[L_SLOTS];
    __shared__ int   Lcount, Lnext;

    const int b     = blockIdx.x >> 4;          // 16 windows per b
    const int t0    = (blockIdx.x & 15) << 5;
    const int tid   = threadIdx.x;
    const int w     = tid >> 6;
    const int lane  = tid & 63;
    const int e4    = lane << 2;
    const int nbase = b << 9;

    // A1+A3 (wave 0, no barrier needed: intra-wave LDS ordering):
    // stage window scalars, wave-reduce Smin, walk shared chain L (indices only).
    if (w == 0) {
        float sv = 1e30f;
        if (lane < W_WIN) {
            const int t = t0 + lane;
            sv = S_in[nbase | t];
            const Node nd = nodes[nbase | t];
            wg_S[lane]   = sv;
            wg_g[lane]   = nd.g;
            wg_ngl[lane] = nd.ngl;
        }
        #pragma unroll
        for (int off = 32; off; off >>= 1) sv = fminf(sv, __shfl_xor(sv, off, 64));
        if (lane == 0) {
            const float smin = sv;
            int lc = 0, m = t0 - 1, mn = -1;
            while (m >= 0 && lc < L_SLOTS) {
                const Node nd = nodes[nbase | m];
                Lidx[lc] = m; Lg[lc] = nd.g; ++lc;
                mn = nd.ngl;
                // all window t's have rc = S[t]+g >= smin+g >= 1 here -> chains
                // reaching this node terminate. (fp-safe: per-t rc check governs;
                // overflow falls back to global walk.)
                if (nd.g >= 1.0f - smin) break;
                m = nd.ngl;
            }
            Lcount = lc; Lnext = mn;
        }
    }
    // A2: stage window v rows (all waves), coalesced 1KB/row.
    for (int r = w; r < W_WIN; r += 4) {
        const float4 x = *(const float4*)(v + ((size_t)(t0 + r) * B_DIM + b) * E_DIM + e4);
        *(float4*)&vwin[r][e4] = x;
    }
    __syncthreads();
    // A4: gather L rows.
    const int lc = Lcount;
    for (int r = w; r < lc; r += 4) {
        const int m = Lidx[r];
        const float4 x = *(const float4*)(v + ((size_t)m * B_DIM + b) * E_DIM + e4);
        *(float4*)&vL[r][e4] = x;
    }
    __syncthreads();
    const int lnx = Lnext;

    // Phase B: wave w walks t = t0 + 8w + j, all rows from LDS.
    for (int j = 0; j < 8; ++j) {
        const int tw = (w << 3) | j;
        const int t  = t0 + tw;
        const float S = wg_S[tw];
        float4 acc = make_float4(0.f, 0.f, 0.f, 0.f);
        float prev = 0.f;
        int m = t;
        bool active = true;

        // in-window part of the chain
        while (active && m >= t0) {
            const int k = m - t0;
            const float g  = wg_g[k];
            const float rc = S + g;
            const float cur = fminf(rc, 1.f);
            const float wt  = cur - prev; prev = cur;
            const float4 vv = *(const float4*)&vwin[k][e4];
            acc.x += wt * vv.x; acc.y += wt * vv.y;
            acc.z += wt * vv.z; acc.w += wt * vv.w;
            if (rc >= 1.f) { active = false; break; }
            m = wg_ngl[k];
            if (m < 0) active = false;
        }
        // staged shared-suffix L
        if (active && m >= 0) {
            int i = 0;
            while (i < lc && Lidx[i] != m) ++i;   // entry point (<=16 uniform cmps)
            if (i < lc) {
                for (; i < lc; ++i) {
                    const float g  = Lg[i];
                    const float rc = S + g;
                    const float cur = fminf(rc, 1.f);
                    const float wt  = cur - prev; prev = cur;
                    const float4 vv = *(const float4*)&vL[i][e4];
                    acc.x += wt * vv.x; acc.y += wt * vv.y;
                    acc.z += wt * vv.z; acc.w += wt * vv.w;
                    if (rc >= 1.f) { active = false; break; }
                }
                if (active) m = lnx;   // consumed all staged slots
            }
            // global fallback (entry past staged bound, or L overflow) — rare
            while (active && m >= 0) {
                const Node nd = nodes[nbase | m];
                const float rc = S + nd.g;
                const float cur = fminf(rc, 1.f);
                const float wt  = cur - prev; prev = cur;
                const float4 vv = *(const float4*)(v + ((size_t)m * B_DIM + b) * E_DIM + e4);
                acc.x += wt * vv.x; acc.y += wt * vv.y;
                acc.z += wt * vv.z; acc.w += wt * vv.w;
                if (rc >= 1.f) break;
                m = nd.ngl;
            }
        }
        const vfloat4 val = {acc.x, acc.y, acc.z, acc.w};
        __builtin_nontemporal_store(val,
            (vfloat4*)(out + ((size_t)t * B_DIM + b) * E_DIM + e4));
    }
}

extern "C" void kernel_launch(void* const* d_in, const int* in_sizes, int n_in,
                              void* d_out, int out_size, void* d_ws, size_t ws_size,
                              hipStream_t stream) {
    const float* v = (const float*)d_in[0];
    const float* u = (const float*)d_in[1];
    const float* d = (const float*)d_in[2];
    float* out = (float*)d_out;

    float* S    = (float*)d_ws;                                     // 256 KB
    Node*  node = (Node*)((char*)d_ws + (size_t)B_DIM * T_DIM * 4); // 512 KB

    scan_prep<<<dim3(B_DIM), 512, 0, stream>>>(u, d, S, node);
    stack_read<<<dim3((T_DIM / W_WIN) * B_DIM), 256, 0, stream>>>(v, S, node, out);
}

// Round 4
// 131.248 us; speedup vs baseline: 1.1532x; 1.1532x over previous
//
#include <hip/hip_runtime.h>

#define T_DIM 512
#define B_DIM 128
#define E_DIM 256
#define NEG_INF (-1e30f)

typedef float vfloat4 __attribute__((ext_vector_type(4)));  // native vec for nt-store

// Closed-form stack math (exact max-plus identity):
//   rc_t[tau] = S[t] + max_{m in [tau,t]} g[m],  S = incl. prefix sum of (d-u),
//   g[m] = d[m] - S[m].
//   W[t][tau] != 0 only at right-to-left records of g (NGL chain from t),
//   truncated once S[t] + g[m] >= 1.

struct Node { float g; int ngl; };   // g value + next-greater-to-left index

// Kernel 1: per-b prep. Shuffle wave-scan for S; sparse-table (range-max
// binary descend) for NGL: fixed 10 LDS probes per thread, no divergent scans.
__global__ void __launch_bounds__(512) scan_prep(
    const float* __restrict__ u, const float* __restrict__ d,
    float* __restrict__ S_out, Node* __restrict__ nodes)
{
    const int b    = blockIdx.x;
    const int t    = threadIdx.x;
    const int lane = t & 63;
    const int w    = t >> 6;          // 8 waves

    __shared__ float wsum[8];
    __shared__ float wpre[8];
    __shared__ float M[10][T_DIM];    // M[k][i] = max g over [max(0,i-2^k+1), i]

    const float dv = d[t * B_DIM + b];
    float x = dv - u[t * B_DIM + b];

    // wave-level inclusive scan (6 shfl steps)
    #pragma unroll
    for (int off = 1; off < 64; off <<= 1) {
        float y = __shfl_up(x, off, 64);
        if (lane >= off) x += y;
    }
    if (lane == 63) wsum[w] = x;
    __syncthreads();
    if (t < 8) {                       // tiny exclusive scan of 8 wave totals
        float s = 0.f;
        for (int i = 0; i < t; ++i) s += wsum[i];
        wpre[t] = s;
    }
    __syncthreads();
    const float S = x + wpre[w];       // inclusive prefix sum of (d-u)
    const float g = dv - S;

    // build sparse table: 9 levels of doubling window max
    M[0][t] = g;
    __syncthreads();
    #pragma unroll
    for (int k = 1; k < 10; ++k) {
        int h = 1 << (k - 1);
        float left = (t >= h) ? M[k - 1][t - h] : NEG_INF;
        float mk = fmaxf(M[k - 1][t], left);
        __syncthreads();               // level k-1 reads done
        M[k][t] = mk;
        __syncthreads();
    }

    // binary descend: largest m < t with g[m] > g (strict); else -1.
    int m = t - 1;
    #pragma unroll
    for (int k = 9; k >= 0; --k) {
        if (m >= 0 && M[k][m] <= g) m -= (1 << k);
    }
    if (m < 0) m = -1;

    S_out[(b << 9) | t] = S;
    nodes[(b << 9) | t] = Node{g, m};
}

// Kernel 2: TWO chains per wave (the R0-proven best structure), plus
// XCD-chunked block swizzle: consecutive logical blocks (same b, nearby t,
// heavily overlapping NGL chains -> same v rows) land on the SAME XCD, so
// chain row re-reads are served by that XCD's 4MB L2 (~1MB working set
// resident) instead of Infinity Cache. nwg=8192, nwg%8==0 -> bijective.
__global__ void __launch_bounds__(256) stack_read(
    const float* __restrict__ v, const float* __restrict__ S_in,
    const Node* __restrict__ nodes, float* __restrict__ out)
{
    const int bid  = blockIdx.x;                       // 0..8191
    const int swz  = ((bid & 7) << 10) | (bid >> 3);   // XCD-chunked (8 XCDs)
    const int wid  = (swz << 2) | (threadIdx.x >> 6);  // 0..32767
    const int lane = threadIdx.x & 63;
    const int id0  = wid << 1, id1 = id0 | 1;
    const int b0 = id0 >> 9, t0 = id0 & 511;
    const int b1 = id1 >> 9, t1 = id1 & 511;
    const int e4 = lane << 2;

    const float S0 = S_in[id0];
    const float S1 = S_in[id1];
    const Node* __restrict__ nb0 = nodes + (b0 << 9);
    const Node* __restrict__ nb1 = nodes + (b1 << 9);

    float4 acc0 = {0.f,0.f,0.f,0.f}, acc1 = {0.f,0.f,0.f,0.f};
    float prev0 = 0.f, prev1 = 0.f;
    int m0 = t0, m1 = t1;
    bool act0 = true, act1 = true;

    while (act0 || act1) {
        Node nd0, nd1; float4 vv0, vv1;
        if (act0) {
            nd0 = nb0[m0];
            vv0 = *(const float4*)(v + ((size_t)m0 * B_DIM + b0) * E_DIM + e4);
        }
        if (act1) {
            nd1 = nb1[m1];
            vv1 = *(const float4*)(v + ((size_t)m1 * B_DIM + b1) * E_DIM + e4);
        }
        if (act0) {
            float rc = S0 + nd0.g;
            float cur = fminf(rc, 1.f);
            float wt = cur - prev0;
            acc0.x += wt * vv0.x; acc0.y += wt * vv0.y;
            acc0.z += wt * vv0.z; acc0.w += wt * vv0.w;
            prev0 = cur;
            if (rc >= 1.f || nd0.ngl < 0) act0 = false; else m0 = nd0.ngl;
        }
        if (act1) {
            float rc = S1 + nd1.g;
            float cur = fminf(rc, 1.f);
            float wt = cur - prev1;
            acc1.x += wt * vv1.x; acc1.y += wt * vv1.y;
            acc1.z += wt * vv1.z; acc1.w += wt * vv1.w;
            prev1 = cur;
            if (rc >= 1.f || nd1.ngl < 0) act1 = false; else m1 = nd1.ngl;
        }
    }
    // Non-temporal stores: write-once stream, keep it out of L2/L3 so v rows
    // stay cache-resident.
    const vfloat4 o0 = {acc0.x, acc0.y, acc0.z, acc0.w};
    const vfloat4 o1 = {acc1.x, acc1.y, acc1.z, acc1.w};
    __builtin_nontemporal_store(o0,
        (vfloat4*)(out + ((size_t)t0 * B_DIM + b0) * E_DIM + e4));
    __builtin_nontemporal_store(o1,
        (vfloat4*)(out + ((size_t)t1 * B_DIM + b1) * E_DIM + e4));
}

extern "C" void kernel_launch(void* const* d_in, const int* in_sizes, int n_in,
                              void* d_out, int out_size, void* d_ws, size_t ws_size,
                              hipStream_t stream) {
    const float* v = (const float*)d_in[0];
    const float* u = (const float*)d_in[1];
    const float* d = (const float*)d_in[2];
    float* out = (float*)d_out;

    float* S    = (float*)d_ws;                                     // 256 KB
    Node*  node = (Node*)((char*)d_ws + (size_t)B_DIM * T_DIM * 4); // 512 KB

    scan_prep<<<dim3(B_DIM), 512, 0, stream>>>(u, d, S, node);
    stack_read<<<dim3((T_DIM * B_DIM) / 8), 256, 0, stream>>>(v, S, node, out);
}